// Round 5
// baseline (259.405 us; speedup 1.0000x reference)
//
#include <hip/hip_runtime.h>
#include <float.h>

#define B_  8
#define C_  16
#define N_  (B_*C_)
#define F_  256
#define H_  112
#define W_  112
#define HW_ (H_*W_)
#define NB_ 3

#define FPAR 2            // features per wave (processed in parallel)
#define WPB  2            // waves per block
#define FPB  (FPAR*WPB)   // features per block = 4
#define LMS  64           // LDS mask row stride (floats)

// ws layout per cell (16 ints): y0,y1,x0,x1, ys[3], ye[3], xs[3], xe[3]

__global__ __launch_bounds__(256) void bbox_kernel(const int4* __restrict__ mask4,
                                                   int* __restrict__ bb) {
    int n = blockIdx.x, t = threadIdx.x;
    const int4* m = mask4 + (size_t)n * (HW_ / 4);
    int ymin = 1 << 20, ymax = -1, xmin = 1 << 20, xmax = -1;
    // W_/4 = 28 int4 per row; an int4 never straddles rows.
    for (int i = t; i < HW_ / 4; i += 256) {
        int4 v = m[i];
        int y = i / 28;
        int xb = (i - y * 28) * 4;
        if (v.x | v.y | v.z | v.w) { ymin = min(ymin, y); ymax = max(ymax, y); }
        if (v.x) { xmin = min(xmin, xb);     xmax = max(xmax, xb);     }
        if (v.y) { xmin = min(xmin, xb + 1); xmax = max(xmax, xb + 1); }
        if (v.z) { xmin = min(xmin, xb + 2); xmax = max(xmax, xb + 2); }
        if (v.w) { xmin = min(xmin, xb + 3); xmax = max(xmax, xb + 3); }
    }
    #pragma unroll
    for (int off = 32; off; off >>= 1) {
        ymin = min(ymin, __shfl_xor(ymin, off));
        ymax = max(ymax, __shfl_xor(ymax, off));
        xmin = min(xmin, __shfl_xor(xmin, off));
        xmax = max(xmax, __shfl_xor(xmax, off));
    }
    __shared__ int red[4][4];
    int wave = t >> 6;
    if ((t & 63) == 0) {
        red[wave][0] = ymin; red[wave][1] = ymax;
        red[wave][2] = xmin; red[wave][3] = xmax;
    }
    __syncthreads();
    if (t == 0) {
        for (int w = 1; w < 4; ++w) {
            ymin = min(ymin, red[w][0]); ymax = max(ymax, red[w][1]);
            xmin = min(xmin, red[w][2]); xmax = max(xmax, red[w][3]);
        }
        int y0 = ymin, y1 = ymax + 1, x0 = xmin, x1 = xmax + 1;
        int* o = bb + n * 16;
        o[0] = y0; o[1] = y1; o[2] = x0; o[3] = x1;
        int szy = y1 - y0, szx = x1 - x0;
        for (int i = 0; i < NB_; ++i) {
            o[4+i]  = y0 + (i*szy)/NB_;
            o[7+i]  = y0 + ((i+1)*szy + NB_-1)/NB_;
            o[10+i] = x0 + (i*szx)/NB_;
            o[13+i] = x0 + ((i+1)*szx + NB_-1)/NB_;
        }
    }
}

// XGL = log2(x-groups). XG x-groups of float4 columns; RT = 64/XG rows per tile.
// Per y-bin: TPB = 16/RT tiles (16 rows covers max bin length 13); rows clamped
// into the bin -> duplicates, max is idempotent. Fully unrolled: no y tests.
template<int XGL>
__device__ __forceinline__ void pool_body(
        const float* __restrict__ gp0, const float* __restrict__ gp1,
        const float* __restrict__ lm, const int* __restrict__ o,
        float* __restrict__ out, int n, int f0,
        int y0, int x0a, int wbw, int lane)
{
    constexpr int XG  = 1 << XGL;
    constexpr int RT  = 64 >> XGL;
    constexpr int TPB = 16 / RT;
    int xq = lane & (XG - 1);
    int rg = lane >> XGL;
    // clamp unused x-groups onto group 0: no extra fetch; excluded in epilogue
    int xq4 = (4 * xq < wbw) ? 4 * xq : 0;

    const float* p0 = gp0 + xq4;
    const float* p1 = gp1 + xq4;

    float acc[3][4][FPAR];
    #pragma unroll
    for (int i = 0; i < 3; ++i)
        #pragma unroll
        for (int s = 0; s < 4; ++s)
            #pragma unroll
            for (int pp = 0; pp < FPAR; ++pp) acc[i][s][pp] = -FLT_MAX;

    #pragma unroll
    for (int i = 0; i < 3; ++i) {
        int ys = o[4 + i], yem1 = o[7 + i] - 1;
        #pragma unroll
        for (int t = 0; t < TPB; ++t) {
            int row = ys + RT * t + rg;
            row = min(row, yem1);
            int dy = row - y0;
            float4 mv = *(const float4*)(lm + dy * LMS + 4 * xq);
            float4 c0 = *(const float4*)(p0 + dy * W_);
            float4 c1 = *(const float4*)(p1 + dy * W_);
            float v0[4] = {mv.x*c0.x, mv.y*c0.y, mv.z*c0.z, mv.w*c0.w};
            float v1[4] = {mv.x*c1.x, mv.y*c1.y, mv.z*c1.z, mv.w*c1.w};
            #pragma unroll
            for (int s = 0; s < 4; ++s) {
                acc[i][s][0] = fmaxf(acc[i][s][0], v0[s]);
                acc[i][s][1] = fmaxf(acc[i][s][1], v1[s]);
            }
        }
    }

    // Epilogue. xg UNclamped: clamped/padded lanes fall outside every x-bin.
    int xg = x0a + 4 * xq;
    #pragma unroll
    for (int pp = 0; pp < FPAR; ++pp) {
        float part[9];
        #pragma unroll
        for (int j = 0; j < 3; ++j) {
            int xs = o[10 + j], xe = o[13 + j];
            #pragma unroll
            for (int i = 0; i < 3; ++i) {
                float r = -FLT_MAX;
                #pragma unroll
                for (int s = 0; s < 4; ++s) {
                    int xx = xg + s;
                    float lim = (xx >= xs && xx < xe) ? FLT_MAX : -FLT_MAX;
                    r = fmaxf(r, fminf(acc[i][s][pp], lim));
                }
                part[i * 3 + j] = r;
            }
        }
        #pragma unroll
        for (int off = 32; off; off >>= 1)
            #pragma unroll
            for (int q = 0; q < 9; ++q)
                part[q] = fmaxf(part[q], __shfl_xor(part[q], off));
        float st = part[0];
        #pragma unroll
        for (int q = 1; q < 9; ++q) st = (lane == q) ? part[q] : st;
        if (lane < 9) out[(size_t)(n * F_ + f0 + pp) * 9 + lane] = st;
    }
}

// grid (N_, F_/FPB) = (128, 64); block 128 = 2 waves; wave handles FPAR features.
__global__ __launch_bounds__(128, 8) void pool_kernel(
        const float* __restrict__ feat, const int* __restrict__ mask,
        const int* __restrict__ bb, float* __restrict__ out) {
    int n = blockIdx.x;
    int b = n >> 4;                       // / C_
    const int* o = bb + n * 16;
    int y0 = o[0], x0 = o[2];
    int bh = o[1] - y0, bw = o[3] - x0;   // each in [11,37]
    int x0a = x0 & ~3;
    int wbw = (x0 - x0a) + bw;            // window cols from x0a, <= 38
    int x1 = x0 + bw;

    __shared__ float lm[37 * LMS];        // 9.25 KB -> 16 blocks/CU
    {
        const int* mrow = mask + (size_t)n * HW_ + (size_t)y0 * W_ + x0a;
        int tot = bh * (LMS / 4);
        for (int idx = threadIdx.x; idx < tot; idx += 128) {
            int dy = idx >> 4, g = idx & 15;
            int gx = x0a + 4 * g;
            int4 m4 = *(const int4*)(mrow + (size_t)dy * W_ + 4 * g);
            float4 v;
            v.x = (m4.x && gx     >= x0 && gx     < x1) ? 1.f : 0.f;
            v.y = (m4.y && gx + 1 >= x0 && gx + 1 < x1) ? 1.f : 0.f;
            v.z = (m4.z && gx + 2 >= x0 && gx + 2 < x1) ? 1.f : 0.f;
            v.w = (m4.w && gx + 3 >= x0 && gx + 3 < x1) ? 1.f : 0.f;
            *(float4*)(&lm[dy * LMS + 4 * g]) = v;
        }
    }
    __syncthreads();

    int lane = threadIdx.x & 63, wave = threadIdx.x >> 6;
    int f0 = blockIdx.y * FPB + wave * FPAR;
    const float* gp0 = feat + (size_t)(b * F_ + f0) * HW_ + (size_t)y0 * W_ + x0a;
    const float* gp1 = gp0 + HW_;

    if (wbw <= 32) pool_body<3>(gp0, gp1, lm, o, out, n, f0, y0, x0a, wbw, lane);
    else           pool_body<4>(gp0, gp1, lm, o, out, n, f0, y0, x0a, wbw, lane);
}

extern "C" void kernel_launch(void* const* d_in, const int* in_sizes, int n_in,
                              void* d_out, int out_size, void* d_ws, size_t ws_size,
                              hipStream_t stream) {
    const float* feat = (const float*)d_in[0];
    const int*   mask = (const int*)d_in[1];
    int* bb = (int*)d_ws;

    bbox_kernel<<<N_, 256, 0, stream>>>((const int4*)mask, bb);
    dim3 grid(N_, F_ / FPB);
    pool_kernel<<<grid, 128, 0, stream>>>(feat, mask, bb, (float*)d_out);
}

// Round 7
// 177.440 us; speedup vs baseline: 1.4619x; 1.4619x over previous
//
#include <hip/hip_runtime.h>
#include <float.h>

#define B_  8
#define C_  16
#define N_  (B_*C_)
#define F_  256
#define H_  112
#define W_  112
#define HW_ (H_*W_)
#define NB_ 3

#define FPAR 2            // features per wave
#define WPB  4            // waves per block
#define FPB  (FPAR*WPB)   // features per block = 8
#define LMS  64           // LDS mask row stride (floats); XGL=4 map measured 0 conflicts (R4)

// ws layout per cell (16 ints): y0,y1,x0,x1, ys[3], ye[3], xs[3], xe[3]

__global__ __launch_bounds__(256) void bbox_kernel(const int4* __restrict__ mask4,
                                                   int* __restrict__ bb) {
    int n = blockIdx.x, t = threadIdx.x;
    const int4* m = mask4 + (size_t)n * (HW_ / 4);
    int ymin = 1 << 20, ymax = -1, xmin = 1 << 20, xmax = -1;
    // W_/4 = 28 int4 per row; an int4 never straddles rows.
    for (int i = t; i < HW_ / 4; i += 256) {
        int4 v = m[i];
        int y = i / 28;
        int xb = (i - y * 28) * 4;
        if (v.x | v.y | v.z | v.w) { ymin = min(ymin, y); ymax = max(ymax, y); }
        if (v.x) { xmin = min(xmin, xb);     xmax = max(xmax, xb);     }
        if (v.y) { xmin = min(xmin, xb + 1); xmax = max(xmax, xb + 1); }
        if (v.z) { xmin = min(xmin, xb + 2); xmax = max(xmax, xb + 2); }
        if (v.w) { xmin = min(xmin, xb + 3); xmax = max(xmax, xb + 3); }
    }
    #pragma unroll
    for (int off = 32; off; off >>= 1) {
        ymin = min(ymin, __shfl_xor(ymin, off));
        ymax = max(ymax, __shfl_xor(ymax, off));
        xmin = min(xmin, __shfl_xor(xmin, off));
        xmax = max(xmax, __shfl_xor(xmax, off));
    }
    __shared__ int red[4][4];
    int wave = t >> 6;
    if ((t & 63) == 0) {
        red[wave][0] = ymin; red[wave][1] = ymax;
        red[wave][2] = xmin; red[wave][3] = xmax;
    }
    __syncthreads();
    if (t == 0) {
        for (int w = 1; w < 4; ++w) {
            ymin = min(ymin, red[w][0]); ymax = max(ymax, red[w][1]);
            xmin = min(xmin, red[w][2]); xmax = max(xmax, red[w][3]);
        }
        int y0 = ymin, y1 = ymax + 1, x0 = xmin, x1 = xmax + 1;
        int* o = bb + n * 16;
        o[0] = y0; o[1] = y1; o[2] = x0; o[3] = x1;
        int szy = y1 - y0, szx = x1 - x0;
        for (int i = 0; i < NB_; ++i) {
            o[4+i]  = y0 + (i*szy)/NB_;
            o[7+i]  = y0 + ((i+1)*szy + NB_-1)/NB_;
            o[10+i] = x0 + (i*szx)/NB_;
            o[13+i] = x0 + ((i+1)*szx + NB_-1)/NB_;
        }
    }
}

// grid (N_, F_/FPB) = (128, 32); block 256 = 4 waves; wave handles FPAR features.
// Lane map (XGL=4): xq = lane&15 -> float4 column group; rg = lane>>4 -> row in tile.
// Segmented y-bins: rows min(ys_i + 4t + rg, ye_i-1); bins >=3 rows, duplicates
// are same-address (L1 hit), max idempotent. No per-row bin tests.
__global__ __launch_bounds__(256) void pool_kernel(
        const float* __restrict__ feat, const int* __restrict__ mask,
        const int* __restrict__ bb, float* __restrict__ out) {
    int n = blockIdx.x;
    int b = n >> 4;                       // / C_
    const int* o = bb + n * 16;
    int y0 = o[0], x0 = o[2];
    int bh = o[1] - y0, bw = o[3] - x0;   // each in [11,37]
    int x0a = x0 & ~3;
    int x1 = x0 + bw;

    __shared__ float lm[37 * LMS];        // 9.25 KB
    {
        const int* mrow = mask + (size_t)n * HW_ + (size_t)y0 * W_ + x0a;
        int tot = bh * (LMS / 4);
        for (int idx = threadIdx.x; idx < tot; idx += 256) {
            int dy = idx >> 4, g = idx & 15;
            int gx = x0a + 4 * g;
            int4 m4 = *(const int4*)(mrow + (size_t)dy * W_ + 4 * g);
            float4 v;
            v.x = (m4.x && gx     >= x0 && gx     < x1) ? 1.f : 0.f;
            v.y = (m4.y && gx + 1 >= x0 && gx + 1 < x1) ? 1.f : 0.f;
            v.z = (m4.z && gx + 2 >= x0 && gx + 2 < x1) ? 1.f : 0.f;
            v.w = (m4.w && gx + 3 >= x0 && gx + 3 < x1) ? 1.f : 0.f;
            *(float4*)(&lm[dy * LMS + 4 * g]) = v;
        }
    }
    __syncthreads();

    int lane = threadIdx.x & 63, wave = threadIdx.x >> 6;
    int xq = lane & 15, rg = lane >> 4;
    int wbw = (x0 - x0a) + bw;
    int xq4 = (4 * xq < wbw) ? 4 * xq : 0;   // clamp far lanes; mask=0 + epilogue-excluded
    int f0 = blockIdx.y * FPB + wave * FPAR;
    const float* gp0 = feat + (size_t)(b * F_ + f0) * HW_ + (size_t)y0 * W_ + x0a + xq4;
    const float* gp1 = gp0 + HW_;

    int ys[3] = {o[4], o[5], o[6]};
    int yem1[3] = {o[7] - 1, o[8] - 1, o[9] - 1};
    int maxlen = max(o[7] - o[4], max(o[8] - o[5], o[9] - o[6]));
    int Tmax = (maxlen + 3) >> 2;         // uniform across block

    float acc[3][4][FPAR];
    #pragma unroll
    for (int i = 0; i < 3; ++i)
        #pragma unroll
        for (int s = 0; s < 4; ++s)
            #pragma unroll
            for (int pp = 0; pp < FPAR; ++pp) acc[i][s][pp] = -FLT_MAX;

    for (int t = 0; t < Tmax; ++t) {
        int dy[3];
        #pragma unroll
        for (int i = 0; i < 3; ++i)
            dy[i] = min(ys[i] + 4 * t + rg, yem1[i]) - y0;
        // issue all 9 loads before any use
        float4 mv[3], c0[3], c1[3];
        #pragma unroll
        for (int i = 0; i < 3; ++i) {
            mv[i] = *(const float4*)(lm + dy[i] * LMS + 4 * xq);
            c0[i] = *(const float4*)(gp0 + dy[i] * W_);
            c1[i] = *(const float4*)(gp1 + dy[i] * W_);
        }
        #pragma unroll
        for (int i = 0; i < 3; ++i) {
            float v0[4] = {mv[i].x*c0[i].x, mv[i].y*c0[i].y, mv[i].z*c0[i].z, mv[i].w*c0[i].w};
            float v1[4] = {mv[i].x*c1[i].x, mv[i].y*c1[i].y, mv[i].z*c1[i].z, mv[i].w*c1[i].w};
            #pragma unroll
            for (int s = 0; s < 4; ++s) {
                acc[i][s][0] = fmaxf(acc[i][s][0], v0[s]);
                acc[i][s][1] = fmaxf(acc[i][s][1], v1[s]);
            }
        }
    }

    // Epilogue. xg UNclamped: clamped/padded lanes fall outside every x-bin.
    int xs[3] = {o[10], o[11], o[12]};
    int xe[3] = {o[13], o[14], o[15]};
    int xg = x0a + 4 * xq;
    #pragma unroll
    for (int pp = 0; pp < FPAR; ++pp) {
        float part[9];
        #pragma unroll
        for (int j = 0; j < 3; ++j) {
            #pragma unroll
            for (int i = 0; i < 3; ++i) {
                float r = -FLT_MAX;
                #pragma unroll
                for (int s = 0; s < 4; ++s) {
                    int xx = xg + s;
                    float lim = (xx >= xs[j] && xx < xe[j]) ? FLT_MAX : -FLT_MAX;
                    r = fmaxf(r, fminf(acc[i][s][pp], lim));
                }
                part[i * 3 + j] = r;
            }
        }
        #pragma unroll
        for (int off = 32; off; off >>= 1)
            #pragma unroll
            for (int q = 0; q < 9; ++q)
                part[q] = fmaxf(part[q], __shfl_xor(part[q], off));
        float st = part[0];
        #pragma unroll
        for (int q = 1; q < 9; ++q) st = (lane == q) ? part[q] : st;
        if (lane < 9) out[(size_t)(n * F_ + f0 + pp) * 9 + lane] = st;
    }
}

extern "C" void kernel_launch(void* const* d_in, const int* in_sizes, int n_in,
                              void* d_out, int out_size, void* d_ws, size_t ws_size,
                              hipStream_t stream) {
    const float* feat = (const float*)d_in[0];
    const int*   mask = (const int*)d_in[1];
    int* bb = (int*)d_ws;

    bbox_kernel<<<N_, 256, 0, stream>>>((const int4*)mask, bb);
    dim3 grid(N_, F_ / FPB);
    pool_kernel<<<grid, 256, 0, stream>>>(feat, mask, bb, (float*)d_out);
}

// Round 8
// 174.822 us; speedup vs baseline: 1.4838x; 1.0150x over previous
//
#include <hip/hip_runtime.h>
#include <float.h>

#define B_  8
#define C_  16
#define N_  (B_*C_)
#define F_  256
#define H_  112
#define W_  112
#define HW_ (H_*W_)
#define NB_ 3

#define FPAR 4            // features per wave
#define WPB  2            // waves per block
#define FPB  (FPAR*WPB)   // features per block = 8
#define LMS  64           // LDS mask row stride (floats); conflict-free (R4: 0 conflicts)

// ws layout per cell (16 ints): y0,y1,x0,x1, ys[3], ye[3], xs[3], xe[3]

__global__ __launch_bounds__(256) void bbox_kernel(const int4* __restrict__ mask4,
                                                   int* __restrict__ bb) {
    int n = blockIdx.x, t = threadIdx.x;
    const int4* m = mask4 + (size_t)n * (HW_ / 4);
    int ymin = 1 << 20, ymax = -1, xmin = 1 << 20, xmax = -1;
    // W_/4 = 28 int4 per row; an int4 never straddles rows.
    for (int i = t; i < HW_ / 4; i += 256) {
        int4 v = m[i];
        int y = i / 28;
        int xb = (i - y * 28) * 4;
        if (v.x | v.y | v.z | v.w) { ymin = min(ymin, y); ymax = max(ymax, y); }
        if (v.x) { xmin = min(xmin, xb);     xmax = max(xmax, xb);     }
        if (v.y) { xmin = min(xmin, xb + 1); xmax = max(xmax, xb + 1); }
        if (v.z) { xmin = min(xmin, xb + 2); xmax = max(xmax, xb + 2); }
        if (v.w) { xmin = min(xmin, xb + 3); xmax = max(xmax, xb + 3); }
    }
    #pragma unroll
    for (int off = 32; off; off >>= 1) {
        ymin = min(ymin, __shfl_xor(ymin, off));
        ymax = max(ymax, __shfl_xor(ymax, off));
        xmin = min(xmin, __shfl_xor(xmin, off));
        xmax = max(xmax, __shfl_xor(xmax, off));
    }
    __shared__ int red[4][4];
    int wave = t >> 6;
    if ((t & 63) == 0) {
        red[wave][0] = ymin; red[wave][1] = ymax;
        red[wave][2] = xmin; red[wave][3] = xmax;
    }
    __syncthreads();
    if (t == 0) {
        for (int w = 1; w < 4; ++w) {
            ymin = min(ymin, red[w][0]); ymax = max(ymax, red[w][1]);
            xmin = min(xmin, red[w][2]); xmax = max(xmax, red[w][3]);
        }
        int y0 = ymin, y1 = ymax + 1, x0 = xmin, x1 = xmax + 1;
        int* o = bb + n * 16;
        o[0] = y0; o[1] = y1; o[2] = x0; o[3] = x1;
        int szy = y1 - y0, szx = x1 - x0;
        for (int i = 0; i < NB_; ++i) {
            o[4+i]  = y0 + (i*szy)/NB_;
            o[7+i]  = y0 + ((i+1)*szy + NB_-1)/NB_;
            o[10+i] = x0 + (i*szx)/NB_;
            o[13+i] = x0 + ((i+1)*szx + NB_-1)/NB_;
        }
    }
}

// grid (N_, F_/FPB) = (128, 32); block 128 = 2 waves; wave handles FPAR features.
// Lane map: xq = lane&15 -> float4 column group; rg = lane>>4 -> y-bin (bi=min(rg,2);
// rg3 duplicates bin2 rows: same addresses, max idempotent). One row per bin per
// iteration; rows clamped into the bin (duplicates harmless). No per-row bin tests,
// 3x fewer accumulator registers than the all-bins-per-lane layout.
__global__ __launch_bounds__(128) void pool_kernel(
        const float* __restrict__ feat, const int* __restrict__ mask,
        const int* __restrict__ bb, float* __restrict__ out) {
    int n = blockIdx.x;
    int b = n >> 4;                       // / C_
    const int* o = bb + n * 16;
    int y0 = o[0], x0 = o[2];
    int bh = o[1] - y0, bw = o[3] - x0;   // each in [11,37]
    int x0a = x0 & ~3;
    int x1 = x0 + bw;

    __shared__ float lm[37 * LMS];        // 9.25 KB
    {
        const int* mrow = mask + (size_t)n * HW_ + (size_t)y0 * W_ + x0a;
        int tot = bh * (LMS / 4);
        for (int idx = threadIdx.x; idx < tot; idx += 128) {
            int dy = idx >> 4, g = idx & 15;
            int gx = x0a + 4 * g;
            int4 m4 = *(const int4*)(mrow + (size_t)dy * W_ + 4 * g);
            float4 v;
            v.x = (m4.x && gx     >= x0 && gx     < x1) ? 1.f : 0.f;
            v.y = (m4.y && gx + 1 >= x0 && gx + 1 < x1) ? 1.f : 0.f;
            v.z = (m4.z && gx + 2 >= x0 && gx + 2 < x1) ? 1.f : 0.f;
            v.w = (m4.w && gx + 3 >= x0 && gx + 3 < x1) ? 1.f : 0.f;
            *(float4*)(&lm[dy * LMS + 4 * g]) = v;
        }
    }
    __syncthreads();

    int lane = threadIdx.x & 63, wave = threadIdx.x >> 6;
    int xq = lane & 15, rg = lane >> 4;
    int bi = min(rg, 2);
    int wbw = (x0 - x0a) + bw;
    int xq4 = (4 * xq < wbw) ? 4 * xq : 0;   // clamp far lanes; mask=0 + epilogue-excluded
    int f0 = blockIdx.y * FPB + wave * FPAR;
    const float* gp = feat + (size_t)(b * F_ + f0) * HW_ + (size_t)y0 * W_ + x0a + xq4;

    int ysb  = o[4 + bi];
    int yeb1 = o[7 + bi] - 1;
    int Tmax = max(o[7] - o[4], max(o[8] - o[5], o[9] - o[6]));  // max bin len <= 13

    float acc[4][FPAR];
    #pragma unroll
    for (int s = 0; s < 4; ++s)
        #pragma unroll
        for (int pp = 0; pp < FPAR; ++pp) acc[s][pp] = -FLT_MAX;

    for (int t = 0; t < Tmax; ++t) {
        int dy = min(ysb + t, yeb1) - y0;
        int off = dy * W_;
        float4 mv = *(const float4*)(lm + dy * LMS + 4 * xq);
        float4 c[FPAR];
        #pragma unroll
        for (int pp = 0; pp < FPAR; ++pp)
            c[pp] = *(const float4*)(gp + (size_t)pp * HW_ + off);
        #pragma unroll
        for (int pp = 0; pp < FPAR; ++pp) {
            acc[0][pp] = fmaxf(acc[0][pp], mv.x * c[pp].x);
            acc[1][pp] = fmaxf(acc[1][pp], mv.y * c[pp].y);
            acc[2][pp] = fmaxf(acc[2][pp], mv.z * c[pp].z);
            acc[3][pp] = fmaxf(acc[3][pp], mv.w * c[pp].w);
        }
    }

    // Epilogue. xg UNclamped: clamped/padded lanes fall outside every x-bin.
    int xg = x0a + 4 * xq;
    float lim[3][4];
    #pragma unroll
    for (int j = 0; j < 3; ++j) {
        int xs = o[10 + j], xe = o[13 + j];
        #pragma unroll
        for (int s = 0; s < 4; ++s) {
            int xx = xg + s;
            lim[j][s] = (xx >= xs && xx < xe) ? FLT_MAX : -FLT_MAX;
        }
    }
    #pragma unroll
    for (int pp = 0; pp < FPAR; ++pp) {
        float part[3];
        #pragma unroll
        for (int j = 0; j < 3; ++j) {
            float r = fminf(acc[0][pp], lim[j][0]);
            r = fmaxf(r, fminf(acc[1][pp], lim[j][1]));
            r = fmaxf(r, fminf(acc[2][pp], lim[j][2]));
            r = fmaxf(r, fminf(acc[3][pp], lim[j][3]));
            part[j] = r;
        }
        // reduce within the 16-lane rg-group
        #pragma unroll
        for (int off = 1; off <= 8; off <<= 1) {
            #pragma unroll
            for (int j = 0; j < 3; ++j)
                part[j] = fmaxf(part[j], __shfl_xor(part[j], off));
        }
        if (xq == 0 && rg < 3) {
            float* op = out + (size_t)(n * F_ + f0 + pp) * 9 + rg * 3;
            op[0] = part[0]; op[1] = part[1]; op[2] = part[2];
        }
    }
}

extern "C" void kernel_launch(void* const* d_in, const int* in_sizes, int n_in,
                              void* d_out, int out_size, void* d_ws, size_t ws_size,
                              hipStream_t stream) {
    const float* feat = (const float*)d_in[0];
    const int*   mask = (const int*)d_in[1];
    int* bb = (int*)d_ws;

    bbox_kernel<<<N_, 256, 0, stream>>>((const int4*)mask, bb);
    dim3 grid(N_, F_ / FPB);
    pool_kernel<<<grid, 128, 0, stream>>>(feat, mask, bb, (float*)d_out);
}